// Round 10
// baseline (286.650 us; speedup 1.0000x reference)
//
#include <hip/hip_runtime.h>
#include <hip/hip_fp16.h>

// GCN 2-layer via on-device CSR + gather-aggregation.
// out = A_norm * relu(A_norm * (X W1) + b1) * W2 + b2
// CSR build = two-level counting sort with locality-preserving writes.
// All gather buffers fp16, rows padded to 64 halves (one aligned 128 B line
// per edge-gather); fp32 accumulation. gemm1 = MFMA 16x16x32_f16.

#define NPB 256              // nodes per bucket (pow2, dst>>8)
#define NB_MAX 512           // max buckets supported (N <= 131072)
#define NCH 256              // partition chunks (= WGs)
#define SCAN_BLK 1024        // elements per scan WG

typedef _Float16 f16;
typedef f16 f16x8 __attribute__((ext_vector_type(8)));
typedef float f32x4 __attribute__((ext_vector_type(4)));

// ---- Pass A: per-chunk bucket histogram -> ghist[b*NCH + w] ----
__global__ __launch_bounds__(256) void k_hist(const int* __restrict__ dst, int* __restrict__ ghist,
                                              int E, int NB, int chunk) {
    __shared__ int h[NB_MAX];
    int tid = threadIdx.x, w = blockIdx.x;
    for (int b = tid; b < NB; b += 256) h[b] = 0;
    __syncthreads();
    int beg = w * chunk, end = min(E, beg + chunk);
    for (int e = beg + tid; e < end; e += 256) atomicAdd(&h[dst[e] >> 8], 1);
    __syncthreads();
    for (int b = tid; b < NB; b += 256) ghist[b * NCH + w] = h[b];
}

// ---- 3-phase exclusive scan of ghist[M] -> gbase[M], bucketBase ----
__global__ __launch_bounds__(256) void k_scan_reduce(const int* __restrict__ ghist, int* __restrict__ wsum, int M) {
    __shared__ int s[256];
    int tid = threadIdx.x;
    int base = blockIdx.x * SCAN_BLK + tid * 4;
    int v = 0;
    if (base + 3 < M) {
        int4 r = *reinterpret_cast<const int4*>(&ghist[base]);
        v = r.x + r.y + r.z + r.w;
    } else {
        for (int j = 0; j < 4; ++j) if (base + j < M) v += ghist[base + j];
    }
    s[tid] = v;
    __syncthreads();
    for (int off = 128; off > 0; off >>= 1) {
        if (tid < off) s[tid] += s[tid + off];
        __syncthreads();
    }
    if (tid == 0) wsum[blockIdx.x] = s[0];
}

// single WG: exclusive-scan nw (<=128) block sums in place; set bucketBase[NB]=E
__global__ __launch_bounds__(128) void k_scan_mid(int* __restrict__ wsum, int* __restrict__ bucketBase,
                                                  int nw, int NB, int E) {
    __shared__ int s[128];
    int tid = threadIdx.x;
    int v = (tid < nw) ? wsum[tid] : 0;
    s[tid] = v;
    __syncthreads();
    for (int off = 1; off < 128; off <<= 1) {
        int add = (tid >= off) ? s[tid - off] : 0;
        __syncthreads();
        s[tid] += add;
        __syncthreads();
    }
    if (tid < nw) wsum[tid] = s[tid] - v;  // exclusive
    if (tid == 0) bucketBase[NB] = E;
}

__global__ __launch_bounds__(256) void k_scan_apply(const int* __restrict__ ghist, const int* __restrict__ wsum,
                                                    int* __restrict__ gbase, int* __restrict__ bucketBase, int M) {
    __shared__ int s[256];
    int tid = threadIdx.x;
    int base = blockIdx.x * SCAN_BLK + tid * 4;
    int e[4];
    int v = 0;
#pragma unroll
    for (int j = 0; j < 4; ++j) {
        int val = (base + j < M) ? ghist[base + j] : 0;
        e[j] = v;  // thread-local exclusive prefix
        v += val;
    }
    s[tid] = v;
    __syncthreads();
    for (int off = 1; off < 256; off <<= 1) {
        int add = (tid >= off) ? s[tid - off] : 0;
        __syncthreads();
        s[tid] += add;
        __syncthreads();
    }
    int tbase = wsum[blockIdx.x] + s[tid] - v;
#pragma unroll
    for (int j = 0; j < 4; ++j) {
        int i = base + j;
        if (i < M) {
            int g = tbase + e[j];
            gbase[i] = g;
            if ((i & (NCH - 1)) == 0) bucketBase[i / NCH] = g;  // first chunk of bucket
        }
    }
}

// ---- Pass B: partition edges into WG-private contiguous runs ----
__global__ __launch_bounds__(256) void k_partition(const int* __restrict__ src, const int* __restrict__ dst,
                                                   const int* __restrict__ gbase, unsigned int* __restrict__ ebuf,
                                                   int E, int NB, int chunk) {
    __shared__ int cur[NB_MAX];
    int tid = threadIdx.x, w = blockIdx.x;
    for (int b = tid; b < NB; b += 256) cur[b] = gbase[b * NCH + w];
    __syncthreads();
    int beg = w * chunk, end = min(E, beg + chunk);
    for (int e = beg + tid; e < end; e += 256) {
        int d = dst[e];
        int b = d >> 8;
        int pos = atomicAdd(&cur[b], 1);
        ebuf[pos] = (unsigned int)src[e] | ((unsigned int)(d & 255) << 24);  // src < 2^24
    }
}

// ---- Pass C: per-bucket counting sort -> rowptr, dinv, csr ----
__global__ __launch_bounds__(256) void k_csr(const unsigned int* __restrict__ ebuf,
                                             const int* __restrict__ bucketBase,
                                             int* __restrict__ rowptr, float* __restrict__ dinv,
                                             int* __restrict__ csr, int n, int E) {
    __shared__ int cnt[NPB];
    __shared__ int sc[NPB];
    __shared__ int cur[NPB];
    int tid = threadIdx.x, b = blockIdx.x;
    int ebeg = bucketBase[b], eend = bucketBase[b + 1];
    cnt[tid] = 0;
    __syncthreads();
    for (int i = ebeg + tid; i < eend; i += 256) atomicAdd(&cnt[ebuf[i] >> 24], 1);
    __syncthreads();
    int v = cnt[tid];
    sc[tid] = v;
    __syncthreads();
    for (int off = 1; off < 256; off <<= 1) {
        int add = (tid >= off) ? sc[tid - off] : 0;
        __syncthreads();
        sc[tid] += add;
        __syncthreads();
    }
    int ex = sc[tid] - v;  // exclusive
    cur[tid] = ex;
    int node = b * NPB + tid;
    if (node < n) {
        rowptr[node] = ebeg + ex;
        dinv[node] = rsqrtf((float)(v + 1));  // +1 self-loop
    }
    if (b == 0 && tid == 0) rowptr[n] = E;
    __syncthreads();
    for (int i = ebeg + tid; i < eend; i += 256) {
        unsigned int word = ebuf[i];
        int pos = atomicAdd(&cur[word >> 24], 1);
        csr[ebeg + pos] = (int)(word & 0xFFFFFFu);
    }
}

// ---- g1[row] = fp16( (x[row] @ W1) * dinv[row] );  [N,128]@[128,64], MFMA ----
__global__ __launch_bounds__(256) void k_gemm1(const float* __restrict__ x, const float* __restrict__ W1,
                                               const float* __restrict__ dinv, __half* __restrict__ g1,
                                               int n) {
    __shared__ f16 Wt[64][136];   // [col][k], pad 8 halves (17.4 KB)
    int tid = threadIdx.x;
    for (int i = tid; i < 128 * 64; i += 256) {
        int k = i >> 6, c = i & 63;
        Wt[c][k] = (f16)W1[i];
    }
    __syncthreads();

    int wv = tid >> 6, lane = tid & 63;
    int lrow = lane & 15, lk = (lane >> 4) * 8;
    int drow0 = (lane >> 4) * 4, dcol = lane & 15;

    int ntile = (n + 63) >> 6;
    for (int rg = blockIdx.x; rg < ntile; rg += gridDim.x) {
        int arow = rg * 64 + wv * 16 + lrow;
        f16x8 afrag[4];
        if (arow < n) {
            const float* xp = x + (size_t)arow * 128 + lk;
#pragma unroll
            for (int m = 0; m < 4; ++m) {
                float4 lo = *reinterpret_cast<const float4*>(xp + m * 32);
                float4 hi = *reinterpret_cast<const float4*>(xp + m * 32 + 4);
                f16x8 a;
                a[0] = (f16)lo.x; a[1] = (f16)lo.y; a[2] = (f16)lo.z; a[3] = (f16)lo.w;
                a[4] = (f16)hi.x; a[5] = (f16)hi.y; a[6] = (f16)hi.z; a[7] = (f16)hi.w;
                afrag[m] = a;
            }
        } else {
#pragma unroll
            for (int m = 0; m < 4; ++m) afrag[m] = (f16x8)(f16)0.f;
        }
        f32x4 accs[4];
#pragma unroll
        for (int t = 0; t < 4; ++t) {
            f32x4 acc = {0.f, 0.f, 0.f, 0.f};
#pragma unroll
            for (int m = 0; m < 4; ++m) {
                f16x8 b = *reinterpret_cast<const f16x8*>(&Wt[t * 16 + lrow][m * 32 + lk]);
                acc = __builtin_amdgcn_mfma_f32_16x16x32_f16(afrag[m], b, acc, 0, 0, 0);
            }
            accs[t] = acc;
        }
#pragma unroll
        for (int r = 0; r < 4; ++r) {
            int grow = rg * 64 + wv * 16 + drow0 + r;
            if (grow < n) {
                float dd = dinv[grow];
#pragma unroll
                for (int t = 0; t < 4; ++t)
                    g1[(size_t)grow * 64 + t * 16 + dcol] = __float2half_rn(accs[t][r] * dd);
            }
        }
    }
}

__device__ __forceinline__ void acc_u4(float* acc, uint4 r) {
    const __half2* h = reinterpret_cast<const __half2*>(&r);
#pragma unroll
    for (int j = 0; j < 4; ++j) {
        float2 f = __half22float2(h[j]);
        acc[2 * j]     += f.x;
        acc[2 * j + 1] += f.y;
    }
}

// ---- layer-1 aggregation: agg1h[v] = fp16( dinv[v]*(g1[v] + sum g1[s]) ) ----
// wave per node; 8 slots x 8 lanes x uint4; 4-wide load batches.
__global__ __launch_bounds__(256) void k_agg1(const __half* __restrict__ g1, const int* __restrict__ rowptr,
                                              const int* __restrict__ csr, const float* __restrict__ dinv,
                                              __half* __restrict__ agg1h, int n) {
    int lane = threadIdx.x & 63;
    int v = blockIdx.x * 4 + (threadIdx.x >> 6);
    if (v >= n) return;
    int beg = rowptr[v], end = rowptr[v + 1];
    int sub = lane >> 3, fl = lane & 7;
    const __half* gb = g1 + (size_t)fl * 8;
    float acc[8] = {};
    int i = beg + sub;
    int s0 = (i      < end) ? csr[i]      : -1;
    int s1 = (i + 8  < end) ? csr[i + 8]  : -1;
    int s2 = (i + 16 < end) ? csr[i + 16] : -1;
    int s3 = (i + 24 < end) ? csr[i + 24] : -1;
    while (s0 >= 0) {
        uint4 r0, r1, r2, r3;
        bool h1 = s1 >= 0, h2 = s2 >= 0, h3 = s3 >= 0;
        r0 = *reinterpret_cast<const uint4*>(&gb[(size_t)s0 * 64]);
        if (h1) r1 = *reinterpret_cast<const uint4*>(&gb[(size_t)s1 * 64]);
        if (h2) r2 = *reinterpret_cast<const uint4*>(&gb[(size_t)s2 * 64]);
        if (h3) r3 = *reinterpret_cast<const uint4*>(&gb[(size_t)s3 * 64]);
        i += 32;
        s0 = (i      < end) ? csr[i]      : -1;
        s1 = (i + 8  < end) ? csr[i + 8]  : -1;
        s2 = (i + 16 < end) ? csr[i + 16] : -1;
        s3 = (i + 24 < end) ? csr[i + 24] : -1;
        acc_u4(acc, r0);
        if (h1) acc_u4(acc, r1);
        if (h2) acc_u4(acc, r2);
        if (h3) acc_u4(acc, r3);
    }
#pragma unroll
    for (int off = 8; off < 64; off <<= 1)
#pragma unroll
        for (int j = 0; j < 8; ++j) acc[j] += __shfl_xor(acc[j], off);
    if (sub == 0) {
        float self[8] = {};
        acc_u4(self, *reinterpret_cast<const uint4*>(&gb[(size_t)v * 64]));
        float d = dinv[v];
        unsigned uu[4];
#pragma unroll
        for (int j = 0; j < 4; ++j) {
            __half2 p = __floats2half2_rn((acc[2 * j] + self[2 * j]) * d,
                                          (acc[2 * j + 1] + self[2 * j + 1]) * d);
            uu[j] = *reinterpret_cast<unsigned*>(&p);
        }
        uint4 wq = {uu[0], uu[1], uu[2], uu[3]};
        *reinterpret_cast<uint4*>(&agg1h[(size_t)v * 64 + fl * 8]) = wq;
    }
}

// ---- g2[row, 0..39] = fp16( (relu(agg1h[row] + b1) @ W2) * dinv[row] ); pad 40..63 = 0 ----
__global__ __launch_bounds__(256) void k_gemm2(const __half* __restrict__ agg1h, const float* __restrict__ W2,
                                               const float* __restrict__ b1, const float* __restrict__ dinv,
                                               __half* __restrict__ g2, int n) {
    __shared__ float Ws[64 * 40];
    __shared__ float b1s[64];
    __shared__ float xs[32][65];
    int tid = threadIdx.x;
    for (int i = tid; i < 64 * 40; i += 256) Ws[i] = W2[i];
    if (tid < 64) b1s[tid] = b1[tid];
    int nrg = n >> 5;   // n assumed multiple of 32 (100000 = 3125*32)
    int r = tid >> 3, cb = (tid & 7) * 5;
    for (int rg = blockIdx.x; rg < nrg; rg += gridDim.x) {
        __syncthreads();
        int row0 = rg << 5;
        // stage 32 rows: one uint4 (8 halves) per thread
        {
            int rr = tid >> 3, part = (tid & 7) * 8;
            uint4 rv = *reinterpret_cast<const uint4*>(&agg1h[(size_t)(row0 + rr) * 64 + part]);
            const __half2* hp = reinterpret_cast<const __half2*>(&rv);
#pragma unroll
            for (int jj = 0; jj < 4; ++jj) {
                float2 f = __half22float2(hp[jj]);
                float v0 = f.x + b1s[part + 2 * jj];
                float v1 = f.y + b1s[part + 2 * jj + 1];
                xs[rr][part + 2 * jj]     = v0 > 0.f ? v0 : 0.f;
                xs[rr][part + 2 * jj + 1] = v1 > 0.f ? v1 : 0.f;
            }
        }
        __syncthreads();
        float acc[5] = {0.f, 0.f, 0.f, 0.f, 0.f};
#pragma unroll
        for (int k = 0; k < 64; ++k) {
            float xv = xs[r][k];
#pragma unroll
            for (int j = 0; j < 5; ++j) acc[j] += xv * Ws[k * 40 + cb + j];
        }
        int row = row0 + r;
        float di = dinv[row];
#pragma unroll
        for (int j = 0; j < 5; ++j) g2[(size_t)row * 64 + cb + j] = __float2half_rn(acc[j] * di);
        // zero the pad halves 40..63 (32 rows x 24 halves)
        for (int i = tid; i < 32 * 24; i += 256) {
            int rr = i / 24, c = 40 + i - (i / 24) * 24;
            g2[(size_t)(row0 + rr) * 64 + c] = __float2half_rn(0.f);
        }
    }
}

// ---- layer-2 aggregation + bias: out[v] = dinv[v]*(g2[v] + sum g2[s]) + b2 ----
// same structure as k_agg1 on padded rows; lanes fl>=5 compute pad (discarded).
__global__ __launch_bounds__(256) void k_agg2(const __half* __restrict__ g2, const int* __restrict__ rowptr,
                                              const int* __restrict__ csr, const float* __restrict__ dinv,
                                              const float* __restrict__ b2, float* __restrict__ out, int n) {
    int lane = threadIdx.x & 63;
    int v = blockIdx.x * 4 + (threadIdx.x >> 6);
    if (v >= n) return;
    int beg = rowptr[v], end = rowptr[v + 1];
    int sub = lane >> 3, fl = lane & 7;
    const __half* gb = g2 + (size_t)fl * 8;
    float acc[8] = {};
    int i = beg + sub;
    int s0 = (i      < end) ? csr[i]      : -1;
    int s1 = (i + 8  < end) ? csr[i + 8]  : -1;
    int s2 = (i + 16 < end) ? csr[i + 16] : -1;
    int s3 = (i + 24 < end) ? csr[i + 24] : -1;
    while (s0 >= 0) {
        uint4 r0, r1, r2, r3;
        bool h1 = s1 >= 0, h2 = s2 >= 0, h3 = s3 >= 0;
        r0 = *reinterpret_cast<const uint4*>(&gb[(size_t)s0 * 64]);
        if (h1) r1 = *reinterpret_cast<const uint4*>(&gb[(size_t)s1 * 64]);
        if (h2) r2 = *reinterpret_cast<const uint4*>(&gb[(size_t)s2 * 64]);
        if (h3) r3 = *reinterpret_cast<const uint4*>(&gb[(size_t)s3 * 64]);
        i += 32;
        s0 = (i      < end) ? csr[i]      : -1;
        s1 = (i + 8  < end) ? csr[i + 8]  : -1;
        s2 = (i + 16 < end) ? csr[i + 16] : -1;
        s3 = (i + 24 < end) ? csr[i + 24] : -1;
        acc_u4(acc, r0);
        if (h1) acc_u4(acc, r1);
        if (h2) acc_u4(acc, r2);
        if (h3) acc_u4(acc, r3);
    }
#pragma unroll
    for (int off = 8; off < 64; off <<= 1)
#pragma unroll
        for (int j = 0; j < 8; ++j) acc[j] += __shfl_xor(acc[j], off);
    if (sub == 0 && fl < 5) {
        float self[8] = {};
        acc_u4(self, *reinterpret_cast<const uint4*>(&gb[(size_t)v * 64]));
        float d = dinv[v];
        float o[8];
#pragma unroll
        for (int j = 0; j < 8; ++j) o[j] = (acc[j] + self[j]) * d + b2[fl * 8 + j];
        float4 o0 = {o[0], o[1], o[2], o[3]};
        float4 o1 = {o[4], o[5], o[6], o[7]};
        *reinterpret_cast<float4*>(&out[(size_t)v * 40 + fl * 8]) = o0;
        *reinterpret_cast<float4*>(&out[(size_t)v * 40 + fl * 8 + 4]) = o1;
    }
}

extern "C" void kernel_launch(void* const* d_in, const int* in_sizes, int n_in,
                              void* d_out, int out_size, void* d_ws, size_t ws_size,
                              hipStream_t stream) {
    const float* x  = (const float*)d_in[0];
    const int*   ei = (const int*)d_in[1];
    const float* W1 = (const float*)d_in[2];
    const float* b1 = (const float*)d_in[3];
    const float* W2 = (const float*)d_in[4];
    const float* b2 = (const float*)d_in[5];
    float* out = (float*)d_out;

    int N = in_sizes[0] / 128;   // 100000
    int E = in_sizes[1] / 2;     // 1600000
    const int* src = ei;
    const int* dst = ei + E;

    int NB = (N + NPB - 1) / NPB;      // 391 buckets
    int chunk = (E + NCH - 1) / NCH;   // 6250
    int M = NB * NCH;                  // 100096 (assumes <= 128*SCAN_BLK)
    int nw = (M + SCAN_BLK - 1) / SCAN_BLK;  // 98

    char* w = (char*)d_ws;
    int*   ghist      = (int*)w;           w += (size_t)M * 4;
    int*   gbase      = (int*)w;           w += (size_t)M * 4;
    int*   bucketBase = (int*)w;           w += (size_t)(NB + 1) * 4 + 252;
    int*   wsum       = (int*)w;           w += 128 * 4;
    unsigned int* ebuf = (unsigned int*)w; w += (size_t)E * 4;
    int*   rowptr     = (int*)w;           w += (size_t)(N + 1) * 4 + 252;
    float* dinv       = (float*)w;         w += (size_t)N * 4 + 256;
    int*   csr        = (int*)w;           w += (size_t)E * 4;
    __half* g1        = (__half*)w;        w += (size_t)N * 64 * 2;
    __half* agg1h     = (__half*)w;        w += (size_t)N * 64 * 2;
    __half* g2        = (__half*)w;        // N*64*2

    k_hist<<<NCH, 256, 0, stream>>>(dst, ghist, E, NB, chunk);
    k_scan_reduce<<<nw, 256, 0, stream>>>(ghist, wsum, M);
    k_scan_mid<<<1, 128, 0, stream>>>(wsum, bucketBase, nw, NB, E);
    k_scan_apply<<<nw, 256, 0, stream>>>(ghist, wsum, gbase, bucketBase, M);
    k_partition<<<NCH, 256, 0, stream>>>(src, dst, gbase, ebuf, E, NB, chunk);
    k_csr<<<NB, 256, 0, stream>>>(ebuf, bucketBase, rowptr, dinv, csr, N, E);

    k_gemm1<<<1024, 256, 0, stream>>>(x, W1, dinv, g1, N);
    k_agg1<<<(N + 3) / 4, 256, 0, stream>>>(g1, rowptr, csr, dinv, agg1h, N);
    k_gemm2<<<1024, 256, 0, stream>>>(agg1h, W2, b1, dinv, g2, N);
    k_agg2<<<(N + 3) / 4, 256, 0, stream>>>(g2, rowptr, csr, dinv, b2, out, N);
}